// Round 4
// baseline (334.879 us; speedup 1.0000x reference)
//
#include <hip/hip_runtime.h>
#include <hip/hip_bf16.h>

// Problem constants
#define NB 128       // batch (num_sims)
#define NA 64        // num_atoms
#define NE 4032      // edges = NA*(NA-1)
#define KT 2         // edge types
#define BE (NB * NE) // 516096 rows per edge type
#define DV_SIZE 262144
#define DE_SIZE 16515072
#define ZERO_SIZE 1032192

// Pass A (stats): 1008 blocks * 4 waves * 8 tiles * 16 rows = 516096
#define PBLK_A 1008
#define TPW_A 8
// Pass B (out): 672 blocks * 4 waves * 12 tiles * 16 rows = 516096 (3 blocks/CU cap)
#define PBLK_B 672
#define TPW_B 12

typedef __attribute__((ext_vector_type(8))) short short8;
typedef __attribute__((ext_vector_type(4))) float floatx4;

__device__ __forceinline__ float elu(float x) {
    return x > 0.0f ? x : __expf(x) - 1.0f;
}

__device__ __forceinline__ unsigned short f2bf(float x) {  // RNE, used in one-time staging
    unsigned u = __float_as_uint(x);
    return (unsigned short)((u + 0x7FFFu + ((u >> 16) & 1u)) >> 16);
}

// packed f32x2 -> bf16x2 (RNE) — lowers to v_cvt_pk_bf16_f32 on gfx950
__device__ __forceinline__ unsigned pkbf(float a, float b) {
    __hip_bfloat162 h = __float22bfloat162_rn(make_float2(a, b));
    unsigned u;
    __builtin_memcpy(&u, &h, 4);
    return u;
}

__device__ __forceinline__ short8 pack8(float4 a, float4 b) {
    unsigned u[4] = {pkbf(a.x, a.y), pkbf(a.z, a.w), pkbf(b.x, b.y), pkbf(b.z, b.w)};
    short8 r;
    __builtin_memcpy(&r, u, 16);
    return r;
}

// ===========================================================================
// v0 fp32 -> bf16 pre-convert (one-time; removes all x-side cvt from hot loops)
// ===========================================================================
__global__ __launch_bounds__(256) void cvt_v0_kernel(const float* __restrict__ v0,
                                                     unsigned short* __restrict__ v0bf) {
    const int idx = blockIdx.x * 256 + threadIdx.x;  // 65536, 4 elems each
    const float4 v = reinterpret_cast<const float4*>(v0)[idx];
    uint2 r;
    r.x = pkbf(v.x, v.y);
    r.y = pkbf(v.z, v.w);
    reinterpret_cast<uint2*>(v0bf)[idx] = r;
}

// ===========================================================================
// Shared helpers for the edge MFMA kernels
// ===========================================================================
// Weight staging (cooperative, one-time per block). W1:(K,64,64) W2:(K,64,32)
struct SMW {
    short8 wA1[16][64];  // f = ((k*4+mt)*2+kf)   16 KB
    short8 wA2[8][64];   // f = ((k*2+mt2)*2+kf)   8 KB
    float b1s[128];
    float b2s[64];
};

__device__ __forceinline__ void stage_weights(SMW& sm, const float* __restrict__ W1,
                                              const float* __restrict__ b1,
                                              const float* __restrict__ W2,
                                              const float* __restrict__ b2) {
    const int tid = threadIdx.x;
#pragma unroll
    for (int s = 0; s < 4; s++) {
        const int slot = s * 256 + tid;
        const int f = slot >> 6, l = slot & 63;
        const int k = f >> 3, mt = (f >> 1) & 3, kf = f & 1;
        const int g = l >> 4, m15 = l & 15;
        short8 v;
#pragma unroll
        for (int j = 0; j < 8; j++) {
            const int kk = kf * 32 + g * 8 + j;
            v[j] = (short)f2bf(W1[(k * 64 + kk) * 64 + mt * 16 + m15]);
        }
        sm.wA1[f][l] = v;
    }
#pragma unroll
    for (int s = 0; s < 2; s++) {
        const int slot = s * 256 + tid;
        const int f = slot >> 6, l = slot & 63;
        const int k = f >> 2, mt2 = (f >> 1) & 1, kf = f & 1;
        const int g = l >> 4, m15 = l & 15;
        short8 v;
#pragma unroll
        for (int j = 0; j < 8; j++) {
            const int kk = kf * 32 + g * 8 + j;
            v[j] = (short)f2bf(W2[(k * 64 + kk) * 32 + mt2 * 16 + m15]);
        }
        sm.wA2[f][l] = v;
    }
    if (tid < 128) sm.b1s[tid] = b1[tid];
    if (tid < 64) sm.b2s[tid] = b2[tid];
}

// Edge row decode: row -> (x-frag pointers). v0bf is bf16 [B*64][32].
__device__ __forceinline__ void load_xfrags(const unsigned short* __restrict__ v0bf,
                                            int row, int g, short8& bx0, short8& bx1) {
    const int b = row / NE;
    const int e = row - b * NE;
    const int i = e / 63;
    const int p = e - i * 63;
    const int j = p + (p >= i ? 1 : 0);
    bx0 = *(const short8*)(v0bf + ((b * 64 + j) * 32 + g * 8));  // recv
    bx1 = *(const short8*)(v0bf + ((b * 64 + i) * 32 + g * 8));  // send
}

// hbuf XOR-swizzle: 16 rows x 32 dwords (128 B rows), 16B block q at (q ^ (row&7)).
// Write (per mt): lane(g,m15) -> logical dwords 8mt+2g(+1): q=2mt+(g>>1), off=2(g&1).
// Read (kf): lane(g,m15) -> logical dwords 16kf+4g..+3: q=4kf+g.
// Bank analysis: <=2-way on both (2-way is free, m136).

// ===========================================================================
// Pass A: edge MLP -> BN sum/sumsq per (k, ch), bucketed atomics.
// k-split outer loop keeps weight frags at 48 VGPR -> 4 blocks/CU.
// ===========================================================================
__global__ __launch_bounds__(256, 4) void edge_stats_mfma_kernel(
    const unsigned short* __restrict__ v0bf, const float* __restrict__ W1,
    const float* __restrict__ b1, const float* __restrict__ W2,
    const float* __restrict__ b2, float* __restrict__ buckets) {
    __shared__ SMW sm;
    __shared__ unsigned hbuf[4][512];
    stage_weights(sm, W1, b1, W2, b2);
    __syncthreads();

    const int lane = threadIdx.x & 63;
    const int w = threadIdx.x >> 6;
    const int g = lane >> 4, m15 = lane & 15;
    const int gw = blockIdx.x * 4 + w;
    unsigned* hw = &hbuf[w][0];
    const int sw = m15 & 7;            // swizzle key
    const int rbase = m15 * 32;

#pragma unroll 1
    for (int k = 0; k < 2; k++) {
        // weight frags -> registers (invariant across tiles)
        short8 a1r[4][2], a2r[2][2];
#pragma unroll
        for (int mt = 0; mt < 4; mt++)
#pragma unroll
            for (int kf = 0; kf < 2; kf++)
                a1r[mt][kf] = sm.wA1[(k * 4 + mt) * 2 + kf][lane];
#pragma unroll
        for (int mt2 = 0; mt2 < 2; mt2++)
#pragma unroll
            for (int kf = 0; kf < 2; kf++)
                a2r[mt2][kf] = sm.wA2[(k * 2 + mt2) * 2 + kf][lane];

        float st[2][4], sq[2][4];
#pragma unroll
        for (int m = 0; m < 2; m++)
#pragma unroll
            for (int r = 0; r < 4; r++) { st[m][r] = 0.f; sq[m][r] = 0.f; }

#pragma unroll 1
        for (int tt = 0; tt < TPW_A; tt++) {
            const int row = (gw * TPW_A + tt) * 16 + m15;
            short8 bx0, bx1;
            load_xfrags(v0bf, row, g, bx0, bx1);

#pragma unroll
            for (int mt = 0; mt < 4; mt++) {
                const float4 bb = *(const float4*)&sm.b1s[k * 64 + mt * 16 + 4 * g];
                floatx4 acc = {bb.x, bb.y, bb.z, bb.w};
                acc = __builtin_amdgcn_mfma_f32_16x16x32_bf16(a1r[mt][0], bx0, acc, 0, 0, 0);
                acc = __builtin_amdgcn_mfma_f32_16x16x32_bf16(a1r[mt][1], bx1, acc, 0, 0, 0);
                uint2 hv;
                hv.x = pkbf(elu(acc[0]), elu(acc[1]));
                hv.y = pkbf(elu(acc[2]), elu(acc[3]));
                const int q = 2 * mt + (g >> 1);
                *(uint2*)&hw[rbase + ((q ^ sw) << 2) + 2 * (g & 1)] = hv;
            }
            const short8 bh0 = *(const short8*)&hw[rbase + (((g) ^ sw) << 2)];
            const short8 bh1 = *(const short8*)&hw[rbase + (((g + 4) ^ sw) << 2)];
#pragma unroll
            for (int mt2 = 0; mt2 < 2; mt2++) {
                const float4 bb = *(const float4*)&sm.b2s[k * 32 + mt2 * 16 + 4 * g];
                floatx4 acc = {bb.x, bb.y, bb.z, bb.w};
                acc = __builtin_amdgcn_mfma_f32_16x16x32_bf16(a2r[mt2][0], bh0, acc, 0, 0, 0);
                acc = __builtin_amdgcn_mfma_f32_16x16x32_bf16(a2r[mt2][1], bh1, acc, 0, 0, 0);
#pragma unroll
                for (int r = 0; r < 4; r++) {
                    const float v = elu(acc[r]);
                    st[mt2][r] += v;
                    sq[mt2][r] += v * v;
                }
            }
        }

        // flush stats for this k: reduce over the 16 row-lanes, atomics from m15==0
        const int bk = gw & 31;
#pragma unroll
        for (int m = 0; m < 2; m++)
#pragma unroll
            for (int r = 0; r < 4; r++) {
                float s = st[m][r], ss = sq[m][r];
#pragma unroll
                for (int off = 1; off < 16; off <<= 1) {
                    s += __shfl_xor(s, off, 64);
                    ss += __shfl_xor(ss, off, 64);
                }
                if (m15 == 0) {
                    const int ch = m * 16 + 4 * g + r;
                    atomicAdd(&buckets[((bk * KT + k) * 32 + ch) * 2], s);
                    atomicAdd(&buckets[((bk * KT + k) * 32 + ch) * 2 + 1], ss);
                }
            }
    }
}

// ---------------------------------------------------------------------------
// Finalize: fold BN into per-channel affine  af = gamma*rs, cf = beta - mu*af
// ---------------------------------------------------------------------------
__global__ void edge_stats_final_kernel(const float* __restrict__ buckets,
                                        const float* __restrict__ gamma,
                                        const float* __restrict__ beta,
                                        float* __restrict__ statf) {
    const int t = threadIdx.x;
    if (t >= 64) return;
    const int k = t >> 5, c = t & 31;
    float s = 0.0f, ss = 0.0f;
#pragma unroll 1
    for (int bk = 0; bk < 32; bk++) {
        s += buckets[((bk * KT + k) * 32 + c) * 2];
        ss += buckets[((bk * KT + k) * 32 + c) * 2 + 1];
    }
    const float M = (float)BE;
    const float mu = s / M;
    const float var = ss / M - mu * mu;
    const float rs = rsqrtf(var + 1e-5f);
    const float af = gamma[k * 32 + c] * rs;
    statf[t * 2] = af;
    statf[t * 2 + 1] = beta[k * 32 + c] - mu * af;
}

// ===========================================================================
// Pass B: recompute edge MLP (both k in regs), affine + edge_type, write de.
// ===========================================================================
__global__ __launch_bounds__(256, 3) void edge_out_mfma_kernel(
    const unsigned short* __restrict__ v0bf, const float* __restrict__ W1,
    const float* __restrict__ b1, const float* __restrict__ W2,
    const float* __restrict__ b2, const float* __restrict__ statf,
    const float* __restrict__ etype, float* __restrict__ de) {
    __shared__ SMW sm;
    __shared__ unsigned hbuf[4][2][512];   // separate k halves: no WAR serialization
    __shared__ float afs[64], cfs[64];
    stage_weights(sm, W1, b1, W2, b2);
    if (threadIdx.x < 64) {
        afs[threadIdx.x] = statf[threadIdx.x * 2];
        cfs[threadIdx.x] = statf[threadIdx.x * 2 + 1];
    }
    __syncthreads();

    const int lane = threadIdx.x & 63;
    const int w = threadIdx.x >> 6;
    const int g = lane >> 4, m15 = lane & 15;
    const int gw = blockIdx.x * 4 + w;
    const int sw = m15 & 7;
    const int rbase = m15 * 32;

    // all weight frags -> registers (96 VGPR)
    short8 a1r[2][4][2], a2r[2][2][2];
#pragma unroll
    for (int k = 0; k < 2; k++) {
#pragma unroll
        for (int mt = 0; mt < 4; mt++)
#pragma unroll
            for (int kf = 0; kf < 2; kf++)
                a1r[k][mt][kf] = sm.wA1[(k * 4 + mt) * 2 + kf][lane];
#pragma unroll
        for (int mt2 = 0; mt2 < 2; mt2++)
#pragma unroll
            for (int kf = 0; kf < 2; kf++)
                a2r[k][mt2][kf] = sm.wA2[(k * 2 + mt2) * 2 + kf][lane];
    }

#pragma unroll 1
    for (int tt = 0; tt < TPW_B; tt++) {
        const int row = (gw * TPW_B + tt) * 16 + m15;
        short8 bx0, bx1;
        load_xfrags(v0bf, row, g, bx0, bx1);

        float o[2][2][4];
#pragma unroll
        for (int k = 0; k < 2; k++) {
            unsigned* hw = &hbuf[w][k][0];
#pragma unroll
            for (int mt = 0; mt < 4; mt++) {
                const float4 bb = *(const float4*)&sm.b1s[k * 64 + mt * 16 + 4 * g];
                floatx4 acc = {bb.x, bb.y, bb.z, bb.w};
                acc = __builtin_amdgcn_mfma_f32_16x16x32_bf16(a1r[k][mt][0], bx0, acc, 0, 0, 0);
                acc = __builtin_amdgcn_mfma_f32_16x16x32_bf16(a1r[k][mt][1], bx1, acc, 0, 0, 0);
                uint2 hv;
                hv.x = pkbf(elu(acc[0]), elu(acc[1]));
                hv.y = pkbf(elu(acc[2]), elu(acc[3]));
                const int q = 2 * mt + (g >> 1);
                *(uint2*)&hw[rbase + ((q ^ sw) << 2) + 2 * (g & 1)] = hv;
            }
            const short8 bh0 = *(const short8*)&hw[rbase + (((g) ^ sw) << 2)];
            const short8 bh1 = *(const short8*)&hw[rbase + (((g + 4) ^ sw) << 2)];
#pragma unroll
            for (int mt2 = 0; mt2 < 2; mt2++) {
                const float4 bb = *(const float4*)&sm.b2s[k * 32 + mt2 * 16 + 4 * g];
                floatx4 acc = {bb.x, bb.y, bb.z, bb.w};
                acc = __builtin_amdgcn_mfma_f32_16x16x32_bf16(a2r[k][mt2][0], bh0, acc, 0, 0, 0);
                acc = __builtin_amdgcn_mfma_f32_16x16x32_bf16(a2r[k][mt2][1], bh1, acc, 0, 0, 0);
#pragma unroll
                for (int r = 0; r < 4; r++) o[k][mt2][r] = elu(acc[r]);
            }
        }

        const float2 wv = *(const float2*)(etype + (size_t)row * 2);
#pragma unroll
        for (int mt2 = 0; mt2 < 2; mt2++) {
            const float4 a0 = *(const float4*)&afs[mt2 * 16 + 4 * g];
            const float4 c0 = *(const float4*)&cfs[mt2 * 16 + 4 * g];
            const float4 a1 = *(const float4*)&afs[32 + mt2 * 16 + 4 * g];
            const float4 c1 = *(const float4*)&cfs[32 + mt2 * 16 + 4 * g];
            float4 r;
            r.x = wv.x * (a0.x * o[0][mt2][0] + c0.x) + wv.y * (a1.x * o[1][mt2][0] + c1.x);
            r.y = wv.x * (a0.y * o[0][mt2][1] + c0.y) + wv.y * (a1.y * o[1][mt2][1] + c1.y);
            r.z = wv.x * (a0.z * o[0][mt2][2] + c0.z) + wv.y * (a1.z * o[1][mt2][2] + c1.z);
            r.w = wv.x * (a0.w * o[0][mt2][3] + c0.w) + wv.y * (a1.w * o[1][mt2][3] + c1.w);
            *(float4*)(de + (size_t)row * 32 + mt2 * 16 + 4 * g) = r;
        }
    }
}

// ===========================================================================
// AGG: agg[b,j,c4] = (1/64) * sum_{i != j} e0[b, i, pos(i,j), c4]
// Predicated + unroll-4 for memory-level parallelism.
// ===========================================================================
__global__ __launch_bounds__(256) void agg_kernel(const float* __restrict__ e0,
                                                  float* __restrict__ agg) {
    const int f = blockIdx.x * 256 + threadIdx.x;  // 65536 = B*N*8
    const int c4 = f & 7;
    const int jn = (f >> 3) & 63;
    const int b = f >> 9;
    const float4* base = (const float4*)e0 + (size_t)b * 64 * 63 * 8;
    float x = 0.f, y = 0.f, z = 0.f, ww = 0.f;
#pragma unroll 4
    for (int i = 0; i < 64; i++) {
        int p = jn - (jn > i ? 1 : 0);
        p = p > 62 ? 62 : p;
        const float m = (i == jn) ? 0.0f : 1.0f;
        const float4 v = base[(i * 63 + p) * 8 + c4];
        x = fmaf(v.x, m, x);
        y = fmaf(v.y, m, y);
        z = fmaf(v.z, m, z);
        ww = fmaf(v.w, m, ww);
    }
    const float s = 1.0f / 64.0f;
    *(float4*)(agg + (size_t)f * 4) = make_float4(x * s, y * s, z * s, ww * s);
}

// ===========================================================================
// NODE PATH (MFMA, unchanged structure from R3)
// ===========================================================================
struct SMN {
    short8 wA1n[4][64];
    short8 wA2n[4][64];
    float b1s[64];
    float b2s[32];
    unsigned long long hbuf[4][16 * 20];
};

__global__ __launch_bounds__(256) void node_mlp_mfma_kernel(
    const float* __restrict__ agg, const float* __restrict__ W1,
    const float* __restrict__ b1, const float* __restrict__ W2,
    const float* __restrict__ b2, float* __restrict__ o_v,
    float* __restrict__ nbuckets) {
    __shared__ SMN sm;
    const int tid = threadIdx.x;
    {
        const int f = tid >> 6, l = tid & 63;
        const int g = l >> 4, m15 = l & 15;
        short8 v;
#pragma unroll
        for (int j = 0; j < 8; j++)
            v[j] = (short)f2bf(W1[(g * 8 + j) * 64 + f * 16 + m15]);
        sm.wA1n[f][l] = v;
        const int mt2 = f >> 1, kf = f & 1;
        short8 u;
#pragma unroll
        for (int j = 0; j < 8; j++)
            u[j] = (short)f2bf(W2[(kf * 32 + g * 8 + j) * 32 + mt2 * 16 + m15]);
        sm.wA2n[f][l] = u;
    }
    if (tid < 64) sm.b1s[tid] = b1[tid];
    else if (tid < 96) sm.b2s[tid - 64] = b2[tid - 64];
    __syncthreads();

    const int lane = tid & 63;
    const int w = tid >> 6;
    const int g = lane >> 4, m15 = lane & 15;
    const int tile = blockIdx.x * 4 + w;     // 512 tiles
    const int row = tile * 16 + m15;

    const float4* px = (const float4*)(agg + (size_t)row * 32 + g * 8);
    const short8 bx = pack8(px[0], px[1]);

    const char* hbase = (const char*)&sm.hbuf[w][0];
    unsigned long long* hw = &sm.hbuf[w][0];

#pragma unroll
    for (int mt = 0; mt < 4; mt++) {
        const float4 bb = *(const float4*)&sm.b1s[mt * 16 + 4 * g];
        floatx4 acc = {bb.x, bb.y, bb.z, bb.w};
        acc = __builtin_amdgcn_mfma_f32_16x16x32_bf16(sm.wA1n[mt][lane], bx, acc, 0, 0, 0);
        const unsigned lo = pkbf(elu(acc[0]), elu(acc[1]));
        const unsigned hi = pkbf(elu(acc[2]), elu(acc[3]));
        hw[m15 * 20 + mt * 4 + g] = ((unsigned long long)hi << 32) | lo;
    }
    const short8 bh0 = *(const short8*)(hbase + m15 * 160 + 0 + g * 16);
    const short8 bh1 = *(const short8*)(hbase + m15 * 160 + 64 + g * 16);

    const int bk = tile & 31;
#pragma unroll
    for (int mt2 = 0; mt2 < 2; mt2++) {
        const float4 bb = *(const float4*)&sm.b2s[mt2 * 16 + 4 * g];
        floatx4 acc = {bb.x, bb.y, bb.z, bb.w};
        acc = __builtin_amdgcn_mfma_f32_16x16x32_bf16(sm.wA2n[mt2 * 2 + 0][lane], bh0, acc, 0, 0, 0);
        acc = __builtin_amdgcn_mfma_f32_16x16x32_bf16(sm.wA2n[mt2 * 2 + 1][lane], bh1, acc, 0, 0, 0);
        float4 ov;
        ov.x = elu(acc[0]);
        ov.y = elu(acc[1]);
        ov.z = elu(acc[2]);
        ov.w = elu(acc[3]);
        *(float4*)(o_v + (size_t)row * 32 + mt2 * 16 + 4 * g) = ov;
        const float vv[4] = {ov.x, ov.y, ov.z, ov.w};
#pragma unroll
        for (int r = 0; r < 4; r++) {
            float s = vv[r], ss = vv[r] * vv[r];
#pragma unroll
            for (int off = 1; off < 16; off <<= 1) {
                s += __shfl_xor(s, off, 64);
                ss += __shfl_xor(ss, off, 64);
            }
            if (m15 == 0) {
                const int ch = mt2 * 16 + 4 * g + r;
                atomicAdd(&nbuckets[(bk * 32 + ch) * 2], s);
                atomicAdd(&nbuckets[(bk * 32 + ch) * 2 + 1], ss);
            }
        }
    }
}

__global__ void node_stats_final_kernel(const float* __restrict__ nbuckets,
                                        const float* __restrict__ gamma,
                                        const float* __restrict__ beta,
                                        float* __restrict__ statn) {
    const int c = threadIdx.x;
    if (c >= 32) return;
    float s = 0.0f, ss = 0.0f;
#pragma unroll 1
    for (int bk = 0; bk < 32; bk++) {
        s += nbuckets[(bk * 32 + c) * 2];
        ss += nbuckets[(bk * 32 + c) * 2 + 1];
    }
    const float M = 8192.0f;
    const float mu = s / M;
    const float var = ss / M - mu * mu;
    const float rs = rsqrtf(var + 1e-5f);
    const float af = gamma[c] * rs;
    statn[c * 2] = af;
    statn[c * 2 + 1] = beta[c] - mu * af;
}

__global__ __launch_bounds__(256) void node_norm_kernel(
    const float* __restrict__ o_v, const float* __restrict__ statn,
    float* __restrict__ dv) {
    const int f = blockIdx.x * 256 + threadIdx.x;
    const int c = f & 31;
    dv[f] = statn[c * 2] * o_v[f] + statn[c * 2 + 1];
}

// ---------------------------------------------------------------------------
extern "C" void kernel_launch(void* const* d_in, const int* in_sizes, int n_in,
                              void* d_out, int out_size, void* d_ws, size_t ws_size,
                              hipStream_t stream) {
    const float* v0 = (const float*)d_in[0];
    const float* e0 = (const float*)d_in[1];
    const float* etype = (const float*)d_in[2];
    const float* W1v = (const float*)d_in[3];
    const float* b1v = (const float*)d_in[4];
    const float* W2v = (const float*)d_in[5];
    const float* b2v = (const float*)d_in[6];
    const float* gv = (const float*)d_in[7];
    const float* btv = (const float*)d_in[8];
    const float* W1e = (const float*)d_in[9];
    const float* b1e = (const float*)d_in[10];
    const float* W2e = (const float*)d_in[11];
    const float* b2e = (const float*)d_in[12];
    const float* ge = (const float*)d_in[13];
    const float* bte = (const float*)d_in[14];
    float* out = (float*)d_out;

    // Workspace layout (floats)
    float* ws = (float*)d_ws;
    float* buckets = ws;                       // 4096  (edge BN buckets)
    float* statf = ws + 4096;                  // 128
    float* nbuckets = ws + 4224;               // 2048  (node BN buckets)
    float* statn = ws + 6272;                  // 64
    float* agg = ws + 6336;                    // 262144
    float* o_v = ws + 268480;                  // 262144
    unsigned short* v0bf = (unsigned short*)(ws + 530624);  // 262144 bf16

    hipMemsetAsync(buckets, 0, (4096 + 128 + 2048) * sizeof(float), stream);
    hipMemsetAsync(out + DV_SIZE + DE_SIZE, 0, ZERO_SIZE * sizeof(float), stream);

    cvt_v0_kernel<<<256, 256, 0, stream>>>(v0, v0bf);
    agg_kernel<<<256, 256, 0, stream>>>(e0, agg);
    node_mlp_mfma_kernel<<<128, 256, 0, stream>>>(agg, W1v, b1v, W2v, b2v, o_v, nbuckets);
    node_stats_final_kernel<<<1, 64, 0, stream>>>(nbuckets, gv, btv, statn);
    node_norm_kernel<<<1024, 256, 0, stream>>>(o_v, statn, out);
    edge_stats_mfma_kernel<<<PBLK_A, 256, 0, stream>>>(v0bf, W1e, b1e, W2e, b2e, buckets);
    edge_stats_final_kernel<<<1, 64, 0, stream>>>(buckets, ge, bte, statf);
    edge_out_mfma_kernel<<<PBLK_B, 256, 0, stream>>>(v0bf, W1e, b1e, W2e, b2e, statf,
                                                     etype, out + DV_SIZE);
}

// Round 5
// 260.654 us; speedup vs baseline: 1.2848x; 1.2848x over previous
//
#include <hip/hip_runtime.h>
#include <hip/hip_bf16.h>

// Problem constants
#define NB 128       // batch (num_sims)
#define NA 64        // num_atoms
#define NE 4032      // edges = NA*(NA-1)
#define KT 2         // edge types
#define BE (NB * NE) // 516096 rows per edge type
#define DV_SIZE 262144
#define DE_SIZE 16515072
#define ZERO_SIZE 1032192

// Pass A (stats + bf16 o_e store): 1008 blocks * 4 waves * 8 tiles * 16 rows = 516096
#define PBLK_A 1008
#define TPW_A 8

typedef __attribute__((ext_vector_type(8))) short short8;
typedef __attribute__((ext_vector_type(4))) float floatx4;

__device__ __forceinline__ float elu(float x) {
    return x > 0.0f ? x : __expf(x) - 1.0f;
}

__device__ __forceinline__ unsigned short f2bf(float x) {  // RNE, one-time staging
    unsigned u = __float_as_uint(x);
    return (unsigned short)((u + 0x7FFFu + ((u >> 16) & 1u)) >> 16);
}

// packed f32x2 -> bf16x2 (RNE): low 16 = a, high 16 = b
__device__ __forceinline__ unsigned pkbf(float a, float b) {
    __hip_bfloat162 h = __float22bfloat162_rn(make_float2(a, b));
    unsigned u;
    __builtin_memcpy(&u, &h, 4);
    return u;
}

__device__ __forceinline__ short8 pack8(float4 a, float4 b) {
    unsigned u[4] = {pkbf(a.x, a.y), pkbf(a.z, a.w), pkbf(b.x, b.y), pkbf(b.z, b.w)};
    short8 r;
    __builtin_memcpy(&r, u, 16);
    return r;
}

// ===========================================================================
// v0 fp32 -> bf16 pre-convert
// ===========================================================================
__global__ __launch_bounds__(256) void cvt_v0_kernel(const float* __restrict__ v0,
                                                     unsigned short* __restrict__ v0bf) {
    const int idx = blockIdx.x * 256 + threadIdx.x;  // 65536, 4 elems each
    const float4 v = reinterpret_cast<const float4*>(v0)[idx];
    uint2 r;
    r.x = pkbf(v.x, v.y);
    r.y = pkbf(v.z, v.w);
    reinterpret_cast<uint2*>(v0bf)[idx] = r;
}

// ===========================================================================
// Shared helpers for the edge MFMA pass
// ===========================================================================
struct SMW {
    short8 wA1[16][64];  // f = ((k*4+mt)*2+kf)   16 KB
    short8 wA2[8][64];   // f = ((k*2+mt2)*2+kf)   8 KB
    float b1s[128];
    float b2s[64];
};

__device__ __forceinline__ void stage_weights(SMW& sm, const float* __restrict__ W1,
                                              const float* __restrict__ b1,
                                              const float* __restrict__ W2,
                                              const float* __restrict__ b2) {
    const int tid = threadIdx.x;
#pragma unroll
    for (int s = 0; s < 4; s++) {
        const int slot = s * 256 + tid;
        const int f = slot >> 6, l = slot & 63;
        const int k = f >> 3, mt = (f >> 1) & 3, kf = f & 1;
        const int g = l >> 4, m15 = l & 15;
        short8 v;
#pragma unroll
        for (int j = 0; j < 8; j++) {
            const int kk = kf * 32 + g * 8 + j;
            v[j] = (short)f2bf(W1[(k * 64 + kk) * 64 + mt * 16 + m15]);
        }
        sm.wA1[f][l] = v;
    }
#pragma unroll
    for (int s = 0; s < 2; s++) {
        const int slot = s * 256 + tid;
        const int f = slot >> 6, l = slot & 63;
        const int k = f >> 2, mt2 = (f >> 1) & 1, kf = f & 1;
        const int g = l >> 4, m15 = l & 15;
        short8 v;
#pragma unroll
        for (int j = 0; j < 8; j++) {
            const int kk = kf * 32 + g * 8 + j;
            v[j] = (short)f2bf(W2[(k * 64 + kk) * 32 + mt2 * 16 + m15]);
        }
        sm.wA2[f][l] = v;
    }
    if (tid < 128) sm.b1s[tid] = b1[tid];
    if (tid < 64) sm.b2s[tid] = b2[tid];
}

__device__ __forceinline__ void load_xfrags(const unsigned short* __restrict__ v0bf,
                                            int row, int g, short8& bx0, short8& bx1) {
    const int b = row / NE;
    const int e = row - b * NE;
    const int i = e / 63;
    const int p = e - i * 63;
    const int j = p + (p >= i ? 1 : 0);
    bx0 = *(const short8*)(v0bf + ((b * 64 + j) * 32 + g * 8));  // recv
    bx1 = *(const short8*)(v0bf + ((b * 64 + i) * 32 + g * 8));  // send
}

// ===========================================================================
// Pass A: edge MLP -> BN sum/sumsq buckets + bf16 o_e store.
// k-split loop keeps weight frags at 48 VGPR; (256,3) cap=170 -> no spill.
// ===========================================================================
__global__ __launch_bounds__(256, 3) void edge_stats_mfma_kernel(
    const unsigned short* __restrict__ v0bf, const float* __restrict__ W1,
    const float* __restrict__ b1, const float* __restrict__ W2,
    const float* __restrict__ b2, float* __restrict__ buckets,
    unsigned short* __restrict__ o_e) {
    __shared__ SMW sm;
    __shared__ unsigned hbuf[4][512];
    stage_weights(sm, W1, b1, W2, b2);
    __syncthreads();

    const int lane = threadIdx.x & 63;
    const int w = threadIdx.x >> 6;
    const int g = lane >> 4, m15 = lane & 15;
    const int gw = blockIdx.x * 4 + w;
    unsigned* hw = &hbuf[w][0];
    const int sw = m15 & 7;            // hbuf XOR-swizzle key
    const int rbase = m15 * 32;

#pragma unroll 1
    for (int k = 0; k < 2; k++) {
        // weight frags -> registers (invariant across tiles): 12 short8 = 48 VGPR
        short8 a1r[4][2], a2r[2][2];
#pragma unroll
        for (int mt = 0; mt < 4; mt++)
#pragma unroll
            for (int kf = 0; kf < 2; kf++)
                a1r[mt][kf] = sm.wA1[(k * 4 + mt) * 2 + kf][lane];
#pragma unroll
        for (int mt2 = 0; mt2 < 2; mt2++)
#pragma unroll
            for (int kf = 0; kf < 2; kf++)
                a2r[mt2][kf] = sm.wA2[(k * 2 + mt2) * 2 + kf][lane];

        float st[2][4], sq[2][4];
#pragma unroll
        for (int m = 0; m < 2; m++)
#pragma unroll
            for (int r = 0; r < 4; r++) { st[m][r] = 0.f; sq[m][r] = 0.f; }

#pragma unroll 1
        for (int tt = 0; tt < TPW_A; tt++) {
            const int row = (gw * TPW_A + tt) * 16 + m15;
            short8 bx0, bx1;
            load_xfrags(v0bf, row, g, bx0, bx1);

#pragma unroll
            for (int mt = 0; mt < 4; mt++) {
                const float4 bb = *(const float4*)&sm.b1s[k * 64 + mt * 16 + 4 * g];
                floatx4 acc = {bb.x, bb.y, bb.z, bb.w};
                acc = __builtin_amdgcn_mfma_f32_16x16x32_bf16(a1r[mt][0], bx0, acc, 0, 0, 0);
                acc = __builtin_amdgcn_mfma_f32_16x16x32_bf16(a1r[mt][1], bx1, acc, 0, 0, 0);
                uint2 hv;
                hv.x = pkbf(elu(acc[0]), elu(acc[1]));
                hv.y = pkbf(elu(acc[2]), elu(acc[3]));
                const int q = 2 * mt + (g >> 1);
                *(uint2*)&hw[rbase + ((q ^ sw) << 2) + 2 * (g & 1)] = hv;
            }
            const short8 bh0 = *(const short8*)&hw[rbase + (((g) ^ sw) << 2)];
            const short8 bh1 = *(const short8*)&hw[rbase + (((g + 4) ^ sw) << 2)];
#pragma unroll
            for (int mt2 = 0; mt2 < 2; mt2++) {
                const float4 bb = *(const float4*)&sm.b2s[k * 32 + mt2 * 16 + 4 * g];
                floatx4 acc = {bb.x, bb.y, bb.z, bb.w};
                acc = __builtin_amdgcn_mfma_f32_16x16x32_bf16(a2r[mt2][0], bh0, acc, 0, 0, 0);
                acc = __builtin_amdgcn_mfma_f32_16x16x32_bf16(a2r[mt2][1], bh1, acc, 0, 0, 0);
                float v0v = elu(acc[0]), v1v = elu(acc[1]);
                float v2v = elu(acc[2]), v3v = elu(acc[3]);
                st[mt2][0] += v0v; sq[mt2][0] += v0v * v0v;
                st[mt2][1] += v1v; sq[mt2][1] += v1v * v1v;
                st[mt2][2] += v2v; sq[mt2][2] += v2v * v2v;
                st[mt2][3] += v3v; sq[mt2][3] += v3v * v3v;
                uint2 ov;
                ov.x = pkbf(v0v, v1v);
                ov.y = pkbf(v2v, v3v);
                *(uint2*)(o_e + ((size_t)k * BE + row) * 32 + mt2 * 16 + 4 * g) = ov;
            }
        }

        // flush stats for this k
        const int bk = gw & 31;
#pragma unroll
        for (int m = 0; m < 2; m++)
#pragma unroll
            for (int r = 0; r < 4; r++) {
                float s = st[m][r], ss = sq[m][r];
#pragma unroll
                for (int off = 1; off < 16; off <<= 1) {
                    s += __shfl_xor(s, off, 64);
                    ss += __shfl_xor(ss, off, 64);
                }
                if (m15 == 0) {
                    const int ch = m * 16 + 4 * g + r;
                    atomicAdd(&buckets[((bk * KT + k) * 32 + ch) * 2], s);
                    atomicAdd(&buckets[((bk * KT + k) * 32 + ch) * 2 + 1], ss);
                }
            }
    }
}

// ---------------------------------------------------------------------------
// Finalize: fold BN into per-channel affine  af = gamma*rs, cf = beta - mu*af
// ---------------------------------------------------------------------------
__global__ void edge_stats_final_kernel(const float* __restrict__ buckets,
                                        const float* __restrict__ gamma,
                                        const float* __restrict__ beta,
                                        float* __restrict__ statf) {
    const int t = threadIdx.x;
    if (t >= 64) return;
    const int k = t >> 5, c = t & 31;
    float s = 0.0f, ss = 0.0f;
#pragma unroll 1
    for (int bk = 0; bk < 32; bk++) {
        s += buckets[((bk * KT + k) * 32 + c) * 2];
        ss += buckets[((bk * KT + k) * 32 + c) * 2 + 1];
    }
    const float M = (float)BE;
    const float mu = s / M;
    const float var = ss / M - mu * mu;
    const float rs = rsqrtf(var + 1e-5f);
    const float af = gamma[k * 32 + c] * rs;
    statf[t * 2] = af;
    statf[t * 2 + 1] = beta[k * 32 + c] - mu * af;
}

// ===========================================================================
// Pass B: pure memory epilogue — read bf16 o_e (both k planes), apply BN
// affine + edge_type weighting, write fp32 de. No MLP recompute.
// Thread = (row, 8-ch group): 16 B read per plane, 32 B write.
// ===========================================================================
__global__ __launch_bounds__(256) void edge_epilogue_kernel(
    const unsigned short* __restrict__ o_e, const float* __restrict__ etype,
    const float* __restrict__ statf, float* __restrict__ de) {
    __shared__ float afs[64], cfs[64];
    if (threadIdx.x < 64) {
        afs[threadIdx.x] = statf[threadIdx.x * 2];
        cfs[threadIdx.x] = statf[threadIdx.x * 2 + 1];
    }
    __syncthreads();

    const int t = blockIdx.x * 256 + threadIdx.x;  // BE*4 = 2064384
    const int cg = t & 3;
    const int row = t >> 2;
    const uint4 p0 = *(const uint4*)(o_e + (size_t)row * 32 + cg * 8);
    const uint4 p1 = *(const uint4*)(o_e + ((size_t)BE + row) * 32 + cg * 8);
    const float2 wv = *(const float2*)(etype + (size_t)row * 2);
    const unsigned pu0[4] = {p0.x, p0.y, p0.z, p0.w};
    const unsigned pu1[4] = {p1.x, p1.y, p1.z, p1.w};

    float r[8];
#pragma unroll
    for (int u = 0; u < 8; u++) {
        const int ch = cg * 8 + u;
        const float o0 = __uint_as_float((u & 1) ? (pu0[u >> 1] & 0xFFFF0000u)
                                                 : (pu0[u >> 1] << 16));
        const float o1 = __uint_as_float((u & 1) ? (pu1[u >> 1] & 0xFFFF0000u)
                                                 : (pu1[u >> 1] << 16));
        r[u] = wv.x * fmaf(afs[ch], o0, cfs[ch]) +
               wv.y * fmaf(afs[32 + ch], o1, cfs[32 + ch]);
    }
    float4* dst = (float4*)(de + (size_t)row * 32 + cg * 8);
    dst[0] = make_float4(r[0], r[1], r[2], r[3]);
    dst[1] = make_float4(r[4], r[5], r[6], r[7]);
}

// ===========================================================================
// AGG: agg[b,j,c4] = (1/64) * sum_{i != j} e0[b, i, pos(i,j), c4]
// ===========================================================================
__global__ __launch_bounds__(256) void agg_kernel(const float* __restrict__ e0,
                                                  float* __restrict__ agg) {
    const int f = blockIdx.x * 256 + threadIdx.x;  // 65536 = B*N*8
    const int c4 = f & 7;
    const int jn = (f >> 3) & 63;
    const int b = f >> 9;
    const float4* base = (const float4*)e0 + (size_t)b * 64 * 63 * 8;
    float x = 0.f, y = 0.f, z = 0.f, ww = 0.f;
#pragma unroll 4
    for (int i = 0; i < 64; i++) {
        int p = jn - (jn > i ? 1 : 0);
        p = p > 62 ? 62 : p;
        const float m = (i == jn) ? 0.0f : 1.0f;
        const float4 v = base[(i * 63 + p) * 8 + c4];
        x = fmaf(v.x, m, x);
        y = fmaf(v.y, m, y);
        z = fmaf(v.z, m, z);
        ww = fmaf(v.w, m, ww);
    }
    const float s = 1.0f / 64.0f;
    *(float4*)(agg + (size_t)f * 4) = make_float4(x * s, y * s, z * s, ww * s);
}

// ===========================================================================
// NODE PATH (MFMA)
// ===========================================================================
struct SMN {
    short8 wA1n[4][64];
    short8 wA2n[4][64];
    float b1s[64];
    float b2s[32];
    unsigned long long hbuf[4][16 * 20];
};

__global__ __launch_bounds__(256) void node_mlp_mfma_kernel(
    const float* __restrict__ agg, const float* __restrict__ W1,
    const float* __restrict__ b1, const float* __restrict__ W2,
    const float* __restrict__ b2, float* __restrict__ o_v,
    float* __restrict__ nbuckets) {
    __shared__ SMN sm;
    const int tid = threadIdx.x;
    {
        const int f = tid >> 6, l = tid & 63;
        const int g = l >> 4, m15 = l & 15;
        short8 v;
#pragma unroll
        for (int j = 0; j < 8; j++)
            v[j] = (short)f2bf(W1[(g * 8 + j) * 64 + f * 16 + m15]);
        sm.wA1n[f][l] = v;
        const int mt2 = f >> 1, kf = f & 1;
        short8 u;
#pragma unroll
        for (int j = 0; j < 8; j++)
            u[j] = (short)f2bf(W2[(kf * 32 + g * 8 + j) * 32 + mt2 * 16 + m15]);
        sm.wA2n[f][l] = u;
    }
    if (tid < 64) sm.b1s[tid] = b1[tid];
    else if (tid < 96) sm.b2s[tid - 64] = b2[tid - 64];
    __syncthreads();

    const int lane = tid & 63;
    const int w = tid >> 6;
    const int g = lane >> 4, m15 = lane & 15;
    const int tile = blockIdx.x * 4 + w;     // 512 tiles
    const int row = tile * 16 + m15;

    const float4* px = (const float4*)(agg + (size_t)row * 32 + g * 8);
    const short8 bx = pack8(px[0], px[1]);

    const char* hbase = (const char*)&sm.hbuf[w][0];
    unsigned long long* hw = &sm.hbuf[w][0];

#pragma unroll
    for (int mt = 0; mt < 4; mt++) {
        const float4 bb = *(const float4*)&sm.b1s[mt * 16 + 4 * g];
        floatx4 acc = {bb.x, bb.y, bb.z, bb.w};
        acc = __builtin_amdgcn_mfma_f32_16x16x32_bf16(sm.wA1n[mt][lane], bx, acc, 0, 0, 0);
        const unsigned lo = pkbf(elu(acc[0]), elu(acc[1]));
        const unsigned hi = pkbf(elu(acc[2]), elu(acc[3]));
        hw[m15 * 20 + mt * 4 + g] = ((unsigned long long)hi << 32) | lo;
    }
    const short8 bh0 = *(const short8*)(hbase + m15 * 160 + 0 + g * 16);
    const short8 bh1 = *(const short8*)(hbase + m15 * 160 + 64 + g * 16);

    const int bk = tile & 31;
#pragma unroll
    for (int mt2 = 0; mt2 < 2; mt2++) {
        const float4 bb = *(const float4*)&sm.b2s[mt2 * 16 + 4 * g];
        floatx4 acc = {bb.x, bb.y, bb.z, bb.w};
        acc = __builtin_amdgcn_mfma_f32_16x16x32_bf16(sm.wA2n[mt2 * 2 + 0][lane], bh0, acc, 0, 0, 0);
        acc = __builtin_amdgcn_mfma_f32_16x16x32_bf16(sm.wA2n[mt2 * 2 + 1][lane], bh1, acc, 0, 0, 0);
        float4 ov;
        ov.x = elu(acc[0]);
        ov.y = elu(acc[1]);
        ov.z = elu(acc[2]);
        ov.w = elu(acc[3]);
        *(float4*)(o_v + (size_t)row * 32 + mt2 * 16 + 4 * g) = ov;
        const float vv[4] = {ov.x, ov.y, ov.z, ov.w};
#pragma unroll
        for (int r = 0; r < 4; r++) {
            float s = vv[r], ss = vv[r] * vv[r];
#pragma unroll
            for (int off = 1; off < 16; off <<= 1) {
                s += __shfl_xor(s, off, 64);
                ss += __shfl_xor(ss, off, 64);
            }
            if (m15 == 0) {
                const int ch = mt2 * 16 + 4 * g + r;
                atomicAdd(&nbuckets[(bk * 32 + ch) * 2], s);
                atomicAdd(&nbuckets[(bk * 32 + ch) * 2 + 1], ss);
            }
        }
    }
}

__global__ void node_stats_final_kernel(const float* __restrict__ nbuckets,
                                        const float* __restrict__ gamma,
                                        const float* __restrict__ beta,
                                        float* __restrict__ statn) {
    const int c = threadIdx.x;
    if (c >= 32) return;
    float s = 0.0f, ss = 0.0f;
#pragma unroll 1
    for (int bk = 0; bk < 32; bk++) {
        s += nbuckets[(bk * 32 + c) * 2];
        ss += nbuckets[(bk * 32 + c) * 2 + 1];
    }
    const float M = 8192.0f;
    const float mu = s / M;
    const float var = ss / M - mu * mu;
    const float rs = rsqrtf(var + 1e-5f);
    const float af = gamma[c] * rs;
    statn[c * 2] = af;
    statn[c * 2 + 1] = beta[c] - mu * af;
}

__global__ __launch_bounds__(256) void node_norm_kernel(
    const float* __restrict__ o_v, const float* __restrict__ statn,
    float* __restrict__ dv) {
    const int f = blockIdx.x * 256 + threadIdx.x;
    const int c = f & 31;
    dv[f] = statn[c * 2] * o_v[f] + statn[c * 2 + 1];
}

// ---------------------------------------------------------------------------
extern "C" void kernel_launch(void* const* d_in, const int* in_sizes, int n_in,
                              void* d_out, int out_size, void* d_ws, size_t ws_size,
                              hipStream_t stream) {
    const float* v0 = (const float*)d_in[0];
    const float* e0 = (const float*)d_in[1];
    const float* etype = (const float*)d_in[2];
    const float* W1v = (const float*)d_in[3];
    const float* b1v = (const float*)d_in[4];
    const float* W2v = (const float*)d_in[5];
    const float* b2v = (const float*)d_in[6];
    const float* gv = (const float*)d_in[7];
    const float* btv = (const float*)d_in[8];
    const float* W1e = (const float*)d_in[9];
    const float* b1e = (const float*)d_in[10];
    const float* W2e = (const float*)d_in[11];
    const float* b2e = (const float*)d_in[12];
    const float* ge = (const float*)d_in[13];
    const float* bte = (const float*)d_in[14];
    float* out = (float*)d_out;

    // Workspace layout (floats)
    float* ws = (float*)d_ws;
    float* buckets = ws;                       // 4096  (edge BN buckets)
    float* statf = ws + 4096;                  // 128
    float* nbuckets = ws + 4224;               // 2048  (node BN buckets)
    float* statn = ws + 6272;                  // 64
    float* agg = ws + 6336;                    // 262144
    float* o_v = ws + 268480;                  // 262144
    unsigned short* v0bf = (unsigned short*)(ws + 530624);   // 262144 bf16 (131072 floats)
    unsigned short* o_e = (unsigned short*)(ws + 661696);    // 2*BE*32 bf16 = 66 MB

    hipMemsetAsync(buckets, 0, (4096 + 128 + 2048) * sizeof(float), stream);
    hipMemsetAsync(out + DV_SIZE + DE_SIZE, 0, ZERO_SIZE * sizeof(float), stream);

    cvt_v0_kernel<<<256, 256, 0, stream>>>(v0, v0bf);
    agg_kernel<<<256, 256, 0, stream>>>(e0, agg);
    node_mlp_mfma_kernel<<<128, 256, 0, stream>>>(agg, W1v, b1v, W2v, b2v, o_v, nbuckets);
    node_stats_final_kernel<<<1, 64, 0, stream>>>(nbuckets, gv, btv, statn);
    node_norm_kernel<<<1024, 256, 0, stream>>>(o_v, statn, out);
    edge_stats_mfma_kernel<<<PBLK_A, 256, 0, stream>>>(v0bf, W1e, b1e, W2e, b2e,
                                                       buckets, o_e);
    edge_stats_final_kernel<<<1, 64, 0, stream>>>(buckets, ge, bte, statf);
    edge_epilogue_kernel<<<8064, 256, 0, stream>>>(o_e, etype, statf, out + DV_SIZE);
}